// Round 4
// baseline (254.560 us; speedup 1.0000x reference)
//
#include <hip/hip_runtime.h>
#include <math.h>

#define NPTS   4096   // points per set (n == m)
#define NPROJ  2000   // projections
#define NB     512    // threads per block (8 waves)
#define NMERGE 8192   // n + m
#define VPT    16     // values per thread (in registers)

// Rotate-within-chunk swizzle: element e of chunk P lands at (e + (P>>1)) & 15.
// For the chunk-strided access patterns here this gives exactly 2-way bank
// aliasing (free on CDNA4 per m136).
__device__ __forceinline__ int sw(int i) {
    return (i & ~15) | (((i & 15) + (i >> 5)) & 15);
}

// Bitonic local merge of VPT in-register elements, steps j=VPT/2..1, uniform dir.
__device__ __forceinline__ void local_merge(float v[VPT], bool asc) {
    #pragma unroll
    for (int j = VPT / 2; j >= 1; j >>= 1) {
        #pragma unroll
        for (int e = 0; e < VPT; ++e) {
            if ((e & j) == 0) {
                float a = v[e], b = v[e | j];
                float mn = fminf(a, b), mx = fmaxf(a, b);
                v[e]     = asc ? mn : mx;
                v[e | j] = asc ? mx : mn;
            }
        }
    }
}

__global__ __launch_bounds__(NB, 8) void swd_kernel(
    const float* __restrict__ Xs, const float* __restrict__ Xt,
    const float* __restrict__ Us, float* __restrict__ out)
{
    __shared__ float keys[NMERGE];   // sorted u || sorted v (swizzled); 32 KB
    __shared__ float red[15 * 8];    // per-iteration wave partials

    const int tid  = threadIdx.x;
    const int arr  = tid >> 8;       // 0 = Xs, 1 = Xt
    const int c    = tid & 255;      // chunk index within array (16 elems/chunk)
    const int lane = tid & 63;
    const int wid  = tid >> 6;       // 0..7
    const int p    = blockIdx.x;

    const float u00 = Us[p*6+0], u01 = Us[p*6+1];
    const float u10 = Us[p*6+2], u11 = Us[p*6+3];
    const float u20 = Us[p*6+4], u21 = Us[p*6+5];

    const float pi_f   = 3.14159265358979323846f;
    const float inv2pi = 0.15915494309189535f;

    const float* __restrict__ X = arr ? Xt : Xs;

    // ---- angles into registers (atan2 is scale-invariant; F.normalize skipped) ----
    // sched_barrier after each group keeps only 3 float4 loads live (no spill).
    float v[VPT];
    {
        const float4* X4 = (const float4*)(X + c * (VPT * 3));  // 48 floats, 16B aligned
        #pragma unroll
        for (int t = 0; t < 4; ++t) {
            float4 q0 = X4[t*3+0], q1 = X4[t*3+1], q2 = X4[t*3+2];
            #define ANG(x,y,z) ((atan2f(-((x)*u01+(y)*u11+(z)*u21), \
                                        -((x)*u00+(y)*u10+(z)*u20)) + pi_f) * inv2pi)
            v[t*4+0] = ANG(q0.x, q0.y, q0.z);
            v[t*4+1] = ANG(q0.w, q1.x, q1.y);
            v[t*4+2] = ANG(q1.z, q1.w, q2.x);
            v[t*4+3] = ANG(q2.y, q2.z, q2.w);
            #undef ANG
            __builtin_amdgcn_sched_barrier(0);
        }
    }

    // ---- phases k=2..8: intra-thread, compile-time directions ----
    #pragma unroll
    for (int k = 2; k <= 8; k <<= 1) {
        #pragma unroll
        for (int j = k >> 1; j >= 1; j >>= 1) {
            #pragma unroll
            for (int e = 0; e < VPT; ++e) {
                if ((e & j) == 0) {
                    bool asc = ((e & k) == 0);
                    float a = v[e], b = v[e | j];
                    float mn = fminf(a, b), mx = fmaxf(a, b);
                    v[e]     = asc ? mn : mx;
                    v[e | j] = asc ? mx : mn;
                }
            }
        }
    }

    // ---- phase k=16: fully local, direction uniform per thread ----
    local_merge(v, (c & 1) == 0);

    // ---- phases k=32..1024: within-wave shfl_xor exchanges + local merge ----
    #pragma unroll
    for (int k = 32; k <= 1024; k <<= 1) {
        bool asc = ((c & (k >> 4)) == 0);
        #pragma unroll
        for (int d = k >> 5; d >= 1; d >>= 1) {     // j = k/2 .. 16
            bool keepmin = (((c & d) == 0) == asc);
            #pragma unroll
            for (int e = 0; e < VPT; ++e) {
                float o = __shfl_xor(v[e], d, 64);
                v[e] = keepmin ? fminf(v[e], o) : fmaxf(v[e], o);
            }
        }
        local_merge(v, asc);
    }

    // ---- phase k=2048: one cross-wave LDS exchange (d=64), rest in-wave ----
    {
        const bool asc = ((c & 128) == 0);
        #pragma unroll
        for (int e = 0; e < VPT; ++e) keys[sw(tid * VPT + e)] = v[e];
        __syncthreads();
        {
            const int pb = (tid ^ 64) * VPT;
            const bool keepmin = (((c & 64) == 0) == asc);
            #pragma unroll
            for (int e = 0; e < VPT; ++e) {
                float o = keys[sw(pb + e)];
                v[e] = keepmin ? fminf(v[e], o) : fmaxf(v[e], o);
            }
        }
        __syncthreads();
        #pragma unroll
        for (int d = 32; d >= 1; d >>= 1) {
            bool keepmin = (((c & d) == 0) == asc);
            #pragma unroll
            for (int e = 0; e < VPT; ++e) {
                float o = __shfl_xor(v[e], d, 64);
                v[e] = keepmin ? fminf(v[e], o) : fmaxf(v[e], o);
            }
        }
        local_merge(v, asc);
    }

    // ---- phase k=4096 (full ascending merge): cross-wave d=128 then d=64 ----
    #pragma unroll
    for (int D = 128; D >= 64; D >>= 1) {
        #pragma unroll
        for (int e = 0; e < VPT; ++e) keys[sw(tid * VPT + e)] = v[e];
        __syncthreads();
        {
            const int pb = (tid ^ D) * VPT;
            const bool keepmin = ((c & D) == 0);     // asc = true
            #pragma unroll
            for (int e = 0; e < VPT; ++e) {
                float o = keys[sw(pb + e)];
                v[e] = keepmin ? fminf(v[e], o) : fmaxf(v[e], o);
            }
        }
        __syncthreads();
    }
    #pragma unroll
    for (int d = 32; d >= 1; d >>= 1) {
        bool keepmin = ((c & d) == 0);
        #pragma unroll
        for (int e = 0; e < VPT; ++e) {
            float o = __shfl_xor(v[e], d, 64);
            v[e] = keepmin ? fminf(v[e], o) : fmaxf(v[e], o);
        }
    }
    local_merge(v, true);

    // store sorted arrays for the merge
    #pragma unroll
    for (int e = 0; e < VPT; ++e) keys[sw(tid * VPT + e)] = v[e];
    __syncthreads();

    // ---- merge-path merge; keep (delta, c-offset) per element in registers ----
    // Level after merged element = (#u taken) - (#v taken); cdf value = c/4096 exact.
    int c_init;
    unsigned int c8[4] = {0,0,0,0};
    {
        const int d0 = tid * VPT;
        int lo = d0 > NPTS ? d0 - NPTS : 0;
        int hi = d0 < NPTS ? d0 : NPTS;
        while (lo < hi) {                     // ties: u first (stable argsort)
            int mid = (lo + hi) >> 1;
            if (keys[sw(mid)] <= keys[sw(NPTS + (d0 - 1 - mid))]) lo = mid + 1; else hi = mid;
        }
        int i = lo, j = d0 - lo;
        c_init = i - j;
        const float FMAXV = 3.402823466e+38f;
        float cu = (i < NPTS) ? keys[sw(i)] : FMAXV;
        float cv = (j < NPTS) ? keys[sw(NPTS + j)] : FMAXV;
        #pragma unroll
        for (int s = 0; s < VPT; ++s) {
            float cur;
            if (cu <= cv) { cur = cu; ++i; cu = (i < NPTS) ? keys[sw(i)] : FMAXV; }
            else          { cur = cv; ++j; cv = (j < NPTS) ? keys[sw(NPTS + j)] : FMAXV; }
            float nxt = fminf(cu, cv);
            if (nxt == FMAXV) nxt = 1.0f;     // vals_pad appends 1.0
            v[s] = nxt - cur;                 // delta (>= 0)
            int off = (i - j) - c_init;       // in [-16, 16]
            c8[s >> 2] |= ((unsigned int)(off & 0xff)) << ((s & 3) * 8);
        }
    }

    // ---- level median c* via integer bisection (no histogram, no atomics) ----
    int lo_c = -4097, hi_c = 4096;
    #pragma unroll 1
    for (int it = 0; it < 14; ++it) {
        const int mid = (lo_c + hi_c) >> 1;   // uniform across block
        const int thr = mid - c_init;
        float s_loc = 0.0f;
        #pragma unroll
        for (int s = 0; s < VPT; ++s) {
            int off = (int)(c8[s >> 2] << ((3 - (s & 3)) * 8)) >> 24;  // sign-extended byte
            s_loc += (off <= thr) ? v[s] : 0.0f;
        }
        #pragma unroll
        for (int o = 32; o >= 1; o >>= 1) s_loc += __shfl_down(s_loc, o, 64);
        if (lane == 0) red[it * 8 + wid] = s_loc;
        __syncthreads();
        float S = 0.0f;
        #pragma unroll
        for (int w = 0; w < 8; ++w) S += red[it * 8 + w];   // broadcast reads
        if (S >= 0.5f) hi_c = mid; else lo_c = mid;
    }
    const int cstar = hi_c;

    // ---- w1 = (1/4096) * sum delta * |c - c*| ----
    float part = 0.0f;
    {
        const int thr = cstar - c_init;
        #pragma unroll
        for (int s = 0; s < VPT; ++s) {
            int off = (int)(c8[s >> 2] << ((3 - (s & 3)) * 8)) >> 24;
            part += v[s] * fabsf((float)(off - thr));
        }
    }
    #pragma unroll
    for (int o = 32; o >= 1; o >>= 1) part += __shfl_down(part, o, 64);
    if (lane == 0) red[112 + wid] = part;
    __syncthreads();
    if (tid == 0) {
        float w1 = (red[112] + red[113] + red[114] + red[115] +
                    red[116] + red[117] + red[118] + red[119]) * (1.0f / 4096.0f);
        atomicAdd(out, w1 * (1.0f / (float)NPROJ));
    }
}

extern "C" void kernel_launch(void* const* d_in, const int* in_sizes, int n_in,
                              void* d_out, int out_size, void* d_ws, size_t ws_size,
                              hipStream_t stream) {
    const float* Xs = (const float*)d_in[0];
    const float* Xt = (const float*)d_in[1];
    const float* Us = (const float*)d_in[2];
    float* out = (float*)d_out;

    hipMemsetAsync(out, 0, sizeof(float), stream);
    swd_kernel<<<NPROJ, NB, 0, stream>>>(Xs, Xt, Us, out);
}

// Round 5
// 245.696 us; speedup vs baseline: 1.0361x; 1.0361x over previous
//
#include <hip/hip_runtime.h>
#include <math.h>

#define NPTS   4096   // points per set (n == m)
#define NPROJ  2000   // projections
#define NB     512    // threads per block (8 waves)
#define NMERGE 8192   // n + m
#define VPT    16     // values per thread (in registers)

// Rotate-within-chunk swizzle: element e of chunk P lands at (e + (P>>1)) & 15.
// For the chunk-strided access patterns here this gives exactly 2-way bank
// aliasing (free on CDNA4 per m136).
__device__ __forceinline__ int sw(int i) {
    return (i & ~15) | (((i & 15) + (i >> 5)) & 15);
}

// Bitonic local merge of VPT in-register elements, steps j=VPT/2..1, uniform dir.
__device__ __forceinline__ void local_merge(float v[VPT], bool asc) {
    #pragma unroll
    for (int j = VPT / 2; j >= 1; j >>= 1) {
        #pragma unroll
        for (int e = 0; e < VPT; ++e) {
            if ((e & j) == 0) {
                float a = v[e], b = v[e | j];
                float mn = fminf(a, b), mx = fmaxf(a, b);
                v[e]     = asc ? mn : mx;
                v[e | j] = asc ? mx : mn;
            }
        }
    }
}

// (512,4): 128-VGPR ceiling. (512,8) forced VGPR=32 -> 268 MB scratch spill
// (R4, 1.87 TB/s of spill traffic); (256,4)'s 64-cap also spilled (R3).
// Actual need is ~50-64 VGPRs; let the allocator have headroom.
__global__ __launch_bounds__(NB, 4) void swd_kernel(
    const float* __restrict__ Xs, const float* __restrict__ Xt,
    const float* __restrict__ Us, float* __restrict__ out)
{
    __shared__ float keys[NMERGE];   // sorted u || sorted v (swizzled); 32 KB
    __shared__ float red[15 * 8];    // per-iteration wave partials

    const int tid  = threadIdx.x;
    const int arr  = tid >> 8;       // 0 = Xs, 1 = Xt
    const int c    = tid & 255;      // chunk index within array (16 elems/chunk)
    const int lane = tid & 63;
    const int wid  = tid >> 6;       // 0..7
    const int p    = blockIdx.x;

    const float u00 = Us[p*6+0], u01 = Us[p*6+1];
    const float u10 = Us[p*6+2], u11 = Us[p*6+3];
    const float u20 = Us[p*6+4], u21 = Us[p*6+5];

    const float pi_f   = 3.14159265358979323846f;
    const float inv2pi = 0.15915494309189535f;

    const float* __restrict__ X = arr ? Xt : Xs;

    // ---- angles into registers (atan2 is scale-invariant; F.normalize skipped) ----
    // sched_barrier after each group keeps only 3 float4 loads live.
    float v[VPT];
    {
        const float4* X4 = (const float4*)(X + c * (VPT * 3));  // 48 floats, 16B aligned
        #pragma unroll
        for (int t = 0; t < 4; ++t) {
            float4 q0 = X4[t*3+0], q1 = X4[t*3+1], q2 = X4[t*3+2];
            #define ANG(x,y,z) ((atan2f(-((x)*u01+(y)*u11+(z)*u21), \
                                        -((x)*u00+(y)*u10+(z)*u20)) + pi_f) * inv2pi)
            v[t*4+0] = ANG(q0.x, q0.y, q0.z);
            v[t*4+1] = ANG(q0.w, q1.x, q1.y);
            v[t*4+2] = ANG(q1.z, q1.w, q2.x);
            v[t*4+3] = ANG(q2.y, q2.z, q2.w);
            #undef ANG
            __builtin_amdgcn_sched_barrier(0);
        }
    }

    // ---- phases k=2..8: intra-thread, compile-time directions ----
    #pragma unroll
    for (int k = 2; k <= 8; k <<= 1) {
        #pragma unroll
        for (int j = k >> 1; j >= 1; j >>= 1) {
            #pragma unroll
            for (int e = 0; e < VPT; ++e) {
                if ((e & j) == 0) {
                    bool asc = ((e & k) == 0);
                    float a = v[e], b = v[e | j];
                    float mn = fminf(a, b), mx = fmaxf(a, b);
                    v[e]     = asc ? mn : mx;
                    v[e | j] = asc ? mx : mn;
                }
            }
        }
    }

    // ---- phase k=16: fully local, direction uniform per thread ----
    local_merge(v, (c & 1) == 0);

    // ---- phases k=32..1024: within-wave shfl_xor exchanges + local merge ----
    #pragma unroll
    for (int k = 32; k <= 1024; k <<= 1) {
        bool asc = ((c & (k >> 4)) == 0);
        #pragma unroll
        for (int d = k >> 5; d >= 1; d >>= 1) {     // j = k/2 .. 16
            bool keepmin = (((c & d) == 0) == asc);
            #pragma unroll
            for (int e = 0; e < VPT; ++e) {
                float o = __shfl_xor(v[e], d, 64);
                v[e] = keepmin ? fminf(v[e], o) : fmaxf(v[e], o);
            }
        }
        local_merge(v, asc);
    }

    // ---- phase k=2048: one cross-wave LDS exchange (d=64), rest in-wave ----
    {
        const bool asc = ((c & 128) == 0);
        #pragma unroll
        for (int e = 0; e < VPT; ++e) keys[sw(tid * VPT + e)] = v[e];
        __syncthreads();
        {
            const int pb = (tid ^ 64) * VPT;
            const bool keepmin = (((c & 64) == 0) == asc);
            #pragma unroll
            for (int e = 0; e < VPT; ++e) {
                float o = keys[sw(pb + e)];
                v[e] = keepmin ? fminf(v[e], o) : fmaxf(v[e], o);
            }
        }
        __syncthreads();
        #pragma unroll
        for (int d = 32; d >= 1; d >>= 1) {
            bool keepmin = (((c & d) == 0) == asc);
            #pragma unroll
            for (int e = 0; e < VPT; ++e) {
                float o = __shfl_xor(v[e], d, 64);
                v[e] = keepmin ? fminf(v[e], o) : fmaxf(v[e], o);
            }
        }
        local_merge(v, asc);
    }

    // ---- phase k=4096 (full ascending merge): cross-wave d=128 then d=64 ----
    #pragma unroll
    for (int D = 128; D >= 64; D >>= 1) {
        #pragma unroll
        for (int e = 0; e < VPT; ++e) keys[sw(tid * VPT + e)] = v[e];
        __syncthreads();
        {
            const int pb = (tid ^ D) * VPT;
            const bool keepmin = ((c & D) == 0);     // asc = true
            #pragma unroll
            for (int e = 0; e < VPT; ++e) {
                float o = keys[sw(pb + e)];
                v[e] = keepmin ? fminf(v[e], o) : fmaxf(v[e], o);
            }
        }
        __syncthreads();
    }
    #pragma unroll
    for (int d = 32; d >= 1; d >>= 1) {
        bool keepmin = ((c & d) == 0);
        #pragma unroll
        for (int e = 0; e < VPT; ++e) {
            float o = __shfl_xor(v[e], d, 64);
            v[e] = keepmin ? fminf(v[e], o) : fmaxf(v[e], o);
        }
    }
    local_merge(v, true);

    // store sorted arrays for the merge
    #pragma unroll
    for (int e = 0; e < VPT; ++e) keys[sw(tid * VPT + e)] = v[e];
    __syncthreads();

    // ---- merge-path merge; keep (delta, c-offset) per element in registers ----
    // Level after merged element = (#u taken) - (#v taken); cdf value = c/4096 exact.
    int c_init;
    unsigned int c8[4] = {0,0,0,0};
    {
        const int d0 = tid * VPT;
        int lo = d0 > NPTS ? d0 - NPTS : 0;
        int hi = d0 < NPTS ? d0 : NPTS;
        while (lo < hi) {                     // ties: u first (stable argsort)
            int mid = (lo + hi) >> 1;
            if (keys[sw(mid)] <= keys[sw(NPTS + (d0 - 1 - mid))]) lo = mid + 1; else hi = mid;
        }
        int i = lo, j = d0 - lo;
        c_init = i - j;
        const float FMAXV = 3.402823466e+38f;
        float cu = (i < NPTS) ? keys[sw(i)] : FMAXV;
        float cv = (j < NPTS) ? keys[sw(NPTS + j)] : FMAXV;
        #pragma unroll
        for (int s = 0; s < VPT; ++s) {
            float cur;
            if (cu <= cv) { cur = cu; ++i; cu = (i < NPTS) ? keys[sw(i)] : FMAXV; }
            else          { cur = cv; ++j; cv = (j < NPTS) ? keys[sw(NPTS + j)] : FMAXV; }
            float nxt = fminf(cu, cv);
            if (nxt == FMAXV) nxt = 1.0f;     // vals_pad appends 1.0
            v[s] = nxt - cur;                 // delta (>= 0)
            int off = (i - j) - c_init;       // in [-16, 16]
            c8[s >> 2] |= ((unsigned int)(off & 0xff)) << ((s & 3) * 8);
        }
    }

    // ---- level median c* via integer bisection (no histogram, no atomics) ----
    int lo_c = -4097, hi_c = 4096;
    #pragma unroll 1
    for (int it = 0; it < 14; ++it) {
        const int mid = (lo_c + hi_c) >> 1;   // uniform across block
        const int thr = mid - c_init;
        float s_loc = 0.0f;
        #pragma unroll
        for (int s = 0; s < VPT; ++s) {
            int off = (int)(c8[s >> 2] << ((3 - (s & 3)) * 8)) >> 24;  // sign-extended byte
            s_loc += (off <= thr) ? v[s] : 0.0f;
        }
        #pragma unroll
        for (int o = 32; o >= 1; o >>= 1) s_loc += __shfl_down(s_loc, o, 64);
        if (lane == 0) red[it * 8 + wid] = s_loc;
        __syncthreads();
        float S = 0.0f;
        #pragma unroll
        for (int w = 0; w < 8; ++w) S += red[it * 8 + w];   // broadcast reads
        if (S >= 0.5f) hi_c = mid; else lo_c = mid;
    }
    const int cstar = hi_c;

    // ---- w1 = (1/4096) * sum delta * |c - c*| ----
    float part = 0.0f;
    {
        const int thr = cstar - c_init;
        #pragma unroll
        for (int s = 0; s < VPT; ++s) {
            int off = (int)(c8[s >> 2] << ((3 - (s & 3)) * 8)) >> 24;
            part += v[s] * fabsf((float)(off - thr));
        }
    }
    #pragma unroll
    for (int o = 32; o >= 1; o >>= 1) part += __shfl_down(part, o, 64);
    if (lane == 0) red[112 + wid] = part;
    __syncthreads();
    if (tid == 0) {
        float w1 = (red[112] + red[113] + red[114] + red[115] +
                    red[116] + red[117] + red[118] + red[119]) * (1.0f / 4096.0f);
        atomicAdd(out, w1 * (1.0f / (float)NPROJ));
    }
}

extern "C" void kernel_launch(void* const* d_in, const int* in_sizes, int n_in,
                              void* d_out, int out_size, void* d_ws, size_t ws_size,
                              hipStream_t stream) {
    const float* Xs = (const float*)d_in[0];
    const float* Xt = (const float*)d_in[1];
    const float* Us = (const float*)d_in[2];
    float* out = (float*)d_out;

    hipMemsetAsync(out, 0, sizeof(float), stream);
    swd_kernel<<<NPROJ, NB, 0, stream>>>(Xs, Xt, Us, out);
}